// Round 10
// baseline (224.873 us; speedup 1.0000x reference)
//
#include <hip/hip_runtime.h>

// ScRRAMBLe capsule layer — R13: transform re-gridded for DRAM stream locality.
//   A) xr[ch,c,k,m] = sum_{ij in ch} Ci[ij,c,k] * x[ij,m]   (R1 structure)
//   B) y[c,j,l]     = sum_{k,m} Wi[c,j,k,l,m] * xr[c,k,m]
//
// R12 post-mortem: asm-pinned 16-deep per-wave pipeline = NULL (224 vs 221).
// Per-wave depth / occupancy / GLDS all falsified; FETCH == Wi exactly ->
// the cap is RATE. Remaining shared factor of every slow variant: 2048
// blocks streaming 2048 private 64KB Wi slices simultaneously -> DRAM row-
// buffer thrash (~1.9 TB/s). The poison fill on the same memory does ONE
// sliding sequential window at 6.8-7.0 TB/s. R13: 512 blocks = 1 capsule i
// per block (2/CU), each walks a CONTIGUOUS 256KB Wi range across its 4
// j-sub-blocks; xr gathered once; j-loop pipelined with counted vmcnt(16)
// (never 0 mid-loop, T4) + sched_barrier after each wait (rule #18);
// 32KB/wave in flight. Route unchanged (~7us).
// Predicted: transform ~25us, total ~175us, FETCH ~134MB. If ~220 again:
// stream-locality exonerated -> next round surfaces direct counters via
// in-kernel x2 Wi pass.

typedef float f4 __attribute__((ext_vector_type(4)));

#define NCH 4   // ij chunks; xr partials = NCH*512*256 floats = 2 MB in d_ws

// ---------------- Kernel A: routing einsum (R1 lineage, NCH=4) -------------
__global__ __launch_bounds__(256) void route_kernel(
    const float* __restrict__ x,
    const float* __restrict__ Ci,
    float* __restrict__ xr_part)
{
    const int iq  = blockIdx.x;
    const int c   = blockIdx.y;
    const int t   = threadIdx.x;
    const int il  = t >> 6;
    const int g   = (t >> 4) & 3;
    const int mq4 = t & 15;
    const int i   = (iq << 2) + il;

    const f4* __restrict__ Ci4 = (const f4*)Ci;
    const f4* __restrict__ x4  = (const f4*)x;

    __shared__ f4 part[1024];   // [g][il][r][mq4]

    f4 a0 = {0.f,0.f,0.f,0.f};
    f4 a1 = {0.f,0.f,0.f,0.f};
    f4 a2 = {0.f,0.f,0.f,0.f};
    f4 a3 = {0.f,0.f,0.f,0.f};

    const int ijpc = 2048 / NCH;      // 512
    const int sub  = ijpc >> 2;       // 128 per g-subgroup
    const int base = c * ijpc + g * sub;
    #pragma unroll 4
    for (int it = 0; it < sub; ++it) {
        const int ij = base + it;
        const f4 c4 = Ci4[ij * 512 + i];
        const f4 xv = x4[(ij << 4) + mq4];
        a0 += c4.x * xv;
        a1 += c4.y * xv;
        a2 += c4.z * xv;
        a3 += c4.w * xv;
    }

    const int pb = ((g << 2) + il) << 2;
    part[(pb + 0) * 16 + mq4] = a0;
    part[(pb + 1) * 16 + mq4] = a1;
    part[(pb + 2) * 16 + mq4] = a2;
    part[(pb + 3) * 16 + mq4] = a3;
    __syncthreads();

    const int il2 = t >> 6;
    const int r   = (t >> 4) & 3;
    const int mm  = t & 15;
    f4 s = {0.f,0.f,0.f,0.f};
    #pragma unroll
    for (int gg = 0; gg < 4; ++gg)
        s += part[(((gg << 2) + il2) * 4 + r) * 16 + mm];

    f4* __restrict__ xp4 = (f4*)xr_part;
    xp4[(c * 512 + (iq << 2) + il2) * 64 + r * 16 + mm] = s;
}

// ---------------- Kernel B: transform, 1 capsule/block, sequential Wi ------
// grid 512 = capsule i; block 256; wave w owns l in [w*16, w*16+16).
// Block walks Wi[i] = 256 KB contiguous across j=0..3 (64 KB each).
__global__ __launch_bounds__(256, 2) void transform_kernel(
    const float* __restrict__ Wi,
    const float* __restrict__ xr_part,
    float* __restrict__ y)
{
    const int i    = blockIdx.x;
    const int t    = threadIdx.x;
    const int lane = t & 63;
    const int w    = t >> 6;
    const int lq   = lane >> 4;
    const int m16  = lane & 15;
    const int lw   = w << 4;

    const f4* __restrict__ xp4 = (const f4*)xr_part;

    // xr gather once (i fixed for the block); compiler-scheduled, then drained.
    f4 xr0, xr1, xr2, xr3;
    {
        f4 tmp[8];
        #pragma unroll
        for (int ch = 0; ch < 2; ++ch)
            #pragma unroll
            for (int k = 0; k < 4; ++k)
                tmp[(ch << 2) + k] =
                    xp4[(((ch << 9) + i) << 6) + (k << 4) + m16];
        xr0 = tmp[0] + tmp[4];
        xr1 = tmp[1] + tmp[5];
        xr2 = tmp[2] + tmp[6];
        xr3 = tmp[3] + tmp[7];
        #pragma unroll
        for (int ch = 0; ch < 2; ++ch)
            #pragma unroll
            for (int k = 0; k < 4; ++k)
                tmp[(ch << 2) + k] =
                    xp4[((((ch + 2) << 9) + i) << 6) + (k << 4) + m16];
        xr0 += tmp[0] + tmp[4];
        xr1 += tmp[1] + tmp[5];
        xr2 += tmp[2] + tmp[6];
        xr3 += tmp[3] + tmp[7];
    }
    // Enter the asm region with vmcnt == 0 (counting below depends on it).
    asm volatile("s_waitcnt vmcnt(0)" ::: "memory");
    __builtin_amdgcn_sched_barrier(0);

    const float* wp = Wi + ((size_t)i << 16);   // i * 65536 floats (256 KB)

    f4 a0, a1, a2,  a3,  a4,  a5,  a6,  a7;
    f4 a8, a9, a10, a11, a12, a13, a14, a15;
    f4 b0, b1, b2,  b3,  b4,  b5,  b6,  b7;
    f4 b8, b9, b10, b11, b12, b13, b14, b15;

#define WLOAD(var, j, c2, k)                                                 \
    {                                                                        \
        const float* ap = wp + ((j) << 14) + ((k) << 12)                     \
                        + ((lw + ((c2) << 2) + lq) << 6) + (m16 << 2);       \
        asm volatile("global_load_dwordx4 %0, %1, off"                       \
                     : "=v"(var) : "v"(ap));                                 \
    }

#define ISSUE16(p, j)                                                        \
    WLOAD(p##0, j, 0, 0)  WLOAD(p##1, j, 0, 1)                               \
    WLOAD(p##2, j, 0, 2)  WLOAD(p##3, j, 0, 3)                               \
    WLOAD(p##4, j, 1, 0)  WLOAD(p##5, j, 1, 1)                               \
    WLOAD(p##6, j, 1, 2)  WLOAD(p##7, j, 1, 3)                               \
    WLOAD(p##8, j, 2, 0)  WLOAD(p##9, j, 2, 1)                               \
    WLOAD(p##10, j, 2, 2) WLOAD(p##11, j, 2, 3)                              \
    WLOAD(p##12, j, 3, 0) WLOAD(p##13, j, 3, 1)                              \
    WLOAD(p##14, j, 3, 2) WLOAD(p##15, j, 3, 3)

#define CONS1(j, c2, wa, wb, wc, wd)                                         \
    {                                                                        \
        f4 s = wa * xr0 + wb * xr1 + wc * xr2 + wd * xr3;                    \
        float pp = s.x + s.y + s.z + s.w;                                    \
        pp += __shfl_xor(pp, 1);                                             \
        pp += __shfl_xor(pp, 2);                                             \
        pp += __shfl_xor(pp, 4);                                             \
        pp += __shfl_xor(pp, 8);                                             \
        if (m16 == 0)                                                        \
            y[(((i << 2) + (j)) << 6) + lw + ((c2) << 2) + lq] = pp;         \
    }

#define CONSUME16(p, j)                                                      \
    CONS1(j, 0, p##0,  p##1,  p##2,  p##3)                                   \
    CONS1(j, 1, p##4,  p##5,  p##6,  p##7)                                   \
    CONS1(j, 2, p##8,  p##9,  p##10, p##11)                                  \
    CONS1(j, 3, p##12, p##13, p##14, p##15)

#define VMW16  asm volatile("s_waitcnt vmcnt(16)" ::: "memory");             \
               __builtin_amdgcn_sched_barrier(0);
#define VMW0   asm volatile("s_waitcnt vmcnt(0)" ::: "memory");              \
               __builtin_amdgcn_sched_barrier(0);

    // j-pipeline: 32 KB/wave in flight, counted waits, drain only at tail.
    ISSUE16(a, 0)
    ISSUE16(b, 1)
    VMW16  CONSUME16(a, 0)  ISSUE16(a, 2)
    VMW16  CONSUME16(b, 1)  ISSUE16(b, 3)
    VMW16  CONSUME16(a, 2)
    VMW0   CONSUME16(b, 3)

#undef WLOAD
#undef ISSUE16
#undef CONS1
#undef CONSUME16
#undef VMW16
#undef VMW0
}

extern "C" void kernel_launch(void* const* d_in, const int* in_sizes, int n_in,
                              void* d_out, int out_size, void* d_ws, size_t ws_size,
                              hipStream_t stream) {
    const float* x  = (const float*)d_in[0];   // 131072 floats
    const float* Ci = (const float*)d_in[1];   // 2048*512*4 floats (16 MB)
    const float* Wi = (const float*)d_in[2];   // 512*4*4*64*64 floats (134 MB)
    float* y  = (float*)d_out;                 // 512*4*64 floats
    float* xr = (float*)d_ws;                  // 2 MB partials

    route_kernel<<<dim3(128, NCH), 256, 0, stream>>>(x, Ci, xr);
    transform_kernel<<<512, 256, 0, stream>>>(Wi, xr, y);
}